// Round 5
// baseline (499.847 us; speedup 1.0000x reference)
//
#include <hip/hip_runtime.h>
#include <hip/hip_bf16.h>

// ---------------------------------------------------------------------------
// ATTEfficient: s = tanh(X@Ww^T + bw)@v ; segment softmax ; att-pool ; MLP head
// X: [32768,1280] f32, Ww: [1280,1280], v: [1280], W1: [512,1280], W2: [1,512]
// ---------------------------------------------------------------------------

#define TOTAL_ROWS 32768
#define DIM 1280
#define NSEG 128
#define DHEAD 512

typedef _Float16 f16x8 __attribute__((ext_vector_type(8)));
typedef _Float16 f16x4 __attribute__((ext_vector_type(4)));
typedef float f32x4 __attribute__((ext_vector_type(4)));
typedef float f32x16 __attribute__((ext_vector_type(16)));

// ---- workspace layout (bytes) ----
#define OFF_XH   0                            // 32768*1280*2 = 83886080
#define OFF_WH   83886080                     // 1280*1280*2  = 3276800
#define OFF_S    87162880                     // 32768*4      = 131072
#define OFF_ATT  87293952                     // 32768*4      = 131072
#define OFF_SEG  87425024                     // 132*4 -> pad 1024
#define OFF_POOL 87426048                     // 128*1280*4   = 655360
#define OFF_H    88081408                     // 128*512*4    = 262144

__device__ __forceinline__ void load_lds16(const void* g, void* l) {
  __builtin_amdgcn_global_load_lds(
      (const __attribute__((address_space(1))) unsigned int*)g,
      (__attribute__((address_space(3))) unsigned int*)l, 16, 0, 0);
}

__device__ __forceinline__ float tanh_fast(float x) {
  float e = __expf(2.0f * x);
  return 1.0f - 2.0f * __builtin_amdgcn_rcpf(e + 1.0f);
}

// ---- f32 -> f16 conversion for X and W in one launch, 8 elems/thread ----
__global__ void cvt_f16_kernel(const float* __restrict__ a, _Float16* __restrict__ oa,
                               int na8, const float* __restrict__ b,
                               _Float16* __restrict__ ob, int nb8) {
  int i = blockIdx.x * blockDim.x + threadIdx.x;
  const float* in;
  _Float16* out;
  int idx;
  if (i < na8) {
    in = a; out = oa; idx = i;
  } else {
    idx = i - na8;
    if (idx >= nb8) return;
    in = b; out = ob;
  }
  const float4* p = (const float4*)in + (size_t)idx * 2;
  float4 u0 = p[0], u1 = p[1];
  f16x8 h;
  h[0] = (_Float16)u0.x; h[1] = (_Float16)u0.y;
  h[2] = (_Float16)u0.z; h[3] = (_Float16)u0.w;
  h[4] = (_Float16)u1.x; h[5] = (_Float16)u1.y;
  h[6] = (_Float16)u1.z; h[7] = (_Float16)u1.w;
  *((f16x8*)out + idx) = h;
}

// ---- segment boundaries from sorted segment_ids; also zeros s ----
__global__ void segstart_kernel(const int* __restrict__ sid,
                                int* __restrict__ segstart, float* __restrict__ s,
                                int total) {
  int i = blockIdx.x * blockDim.x + threadIdx.x;
  if (i >= total) return;
  s[i] = 0.f;  // zero the GEMM atomic accumulator (ws is 0xAA-poisoned)
  int sg = sid[i];
  if (i == 0) segstart[0] = 0;
  else if (sid[i - 1] != sg) segstart[sg] = i;
  if (i == total - 1) segstart[sg + 1] = total;
}

// ---- fused GEMM + tanh + dot-with-v:  s[i] += sum_j tanh(X_i.W_j + bw_j) v_j
// tile 128x128, BK=64, XOR-swizzled LDS (conflict-free), 32x32x16 MFMA:
// 8 MFMA + 16 ds_read_b128 per wave-iter (4x fewer MFMA ops than 16x16x32).
__global__ __launch_bounds__(256) void gemm_s_kernel(
    const _Float16* __restrict__ X, const _Float16* __restrict__ W,
    const float* __restrict__ v, const float* __restrict__ bw,
    float* __restrict__ s) {
  __shared__ _Float16 As[128 * 64];   // 16 KB, [row][64], chunk-swizzled
  __shared__ _Float16 Bs[128 * 64];   // 16 KB
  const int rowBase = blockIdx.x * 128;
  const int jBase = blockIdx.y * 128;
  const int t = threadIdx.x;
  const int lane = t & 63;
  const int w = t >> 6;
  const int wm = w & 1, wn = w >> 1;
  const int col = lane & 31;   // row (A) / col (B) within a 32-tile
  const int kh = lane >> 5;    // k-half: lane reads k = kstep*16 + kh*8 .. +8

  // LDS fragment base offsets (f16 units) per k-step ks (k=16 each).
  // chunk c = ks*2 + kh; swizzled pos ((c+row)&7) is mt/wm-invariant since
  // mt*32, wm*64 are 0 mod 8. Full offset = base[ks] + mt*2048 (imm 4096 B).
  int aBase[4], bBase[4];
#pragma unroll
  for (int ks = 0; ks < 4; ++ks) {
    int swz = ((ks * 2 + kh + col) & 7) * 8;
    aBase[ks] = (wm * 64 + col) * 64 + swz;
    bBase[ks] = (wn * 64 + col) * 64 + swz;
  }

  // staging: slot l = w*256 + q*64 + lane holds chunk g of row w*32+q*8+(lane>>3)
  const int subrow = lane >> 3;
  const int g = ((lane & 7) - subrow) & 7;
  const _Float16* gA = X + (size_t)(rowBase + w * 32 + subrow) * DIM + g * 8;
  const _Float16* gB = W + (size_t)(jBase + w * 32 + subrow) * DIM + g * 8;

  f32x16 acc[2][2];
#pragma unroll
  for (int i = 0; i < 2; ++i)
#pragma unroll
    for (int j = 0; j < 2; ++j)
#pragma unroll
      for (int r = 0; r < 16; ++r) acc[i][j][r] = 0.f;

  for (int k0 = 0; k0 < DIM; k0 += 64) {
    __syncthreads();
#pragma unroll
    for (int q = 0; q < 4; ++q) {
      load_lds16(gA + k0 + q * (8 * DIM), &As[(w * 256 + q * 64) * 8]);
      load_lds16(gB + k0 + q * (8 * DIM), &Bs[(w * 256 + q * 64) * 8]);
    }
    __syncthreads();

#pragma unroll
    for (int ks = 0; ks < 4; ++ks) {
      f16x8 a0 = *(const f16x8*)&As[aBase[ks]];
      f16x8 a1 = *(const f16x8*)&As[aBase[ks] + 2048];
      f16x8 b0 = *(const f16x8*)&Bs[bBase[ks]];
      f16x8 b1 = *(const f16x8*)&Bs[bBase[ks] + 2048];
      acc[0][0] = __builtin_amdgcn_mfma_f32_32x32x16_f16(a0, b0, acc[0][0], 0, 0, 0);
      acc[0][1] = __builtin_amdgcn_mfma_f32_32x32x16_f16(a0, b1, acc[0][1], 0, 0, 0);
      acc[1][0] = __builtin_amdgcn_mfma_f32_32x32x16_f16(a1, b0, acc[1][0], 0, 0, 0);
      acc[1][1] = __builtin_amdgcn_mfma_f32_32x32x16_f16(a1, b1, acc[1][1], 0, 0, 0);
    }
  }

  // epilogue: 32x32 C/D layout col=lane&31, row=(r&3)+8*(r>>2)+4*(lane>>5)
  const int colBase = jBase + wn * 64 + col;
  float vv[2], bb[2];
#pragma unroll
  for (int nt = 0; nt < 2; ++nt) {
    int j = colBase + nt * 32;
    vv[nt] = v[j];
    bb[nt] = bw[j];
  }
#pragma unroll
  for (int mt = 0; mt < 2; ++mt) {
#pragma unroll
    for (int r = 0; r < 16; ++r) {
      float sumv = tanh_fast(acc[mt][0][r] + bb[0]) * vv[0] +
                   tanh_fast(acc[mt][1][r] + bb[1]) * vv[1];
      sumv += __shfl_xor(sumv, 1);
      sumv += __shfl_xor(sumv, 2);
      sumv += __shfl_xor(sumv, 4);
      sumv += __shfl_xor(sumv, 8);
      sumv += __shfl_xor(sumv, 16);
      if (col == 0) {
        int row = rowBase + wm * 64 + mt * 32 + (r & 3) + 8 * (r >> 2) + 4 * kh;
        atomicAdd(&s[row], sumv);
      }
    }
  }
}

// ---- per-segment stable softmax -> att; also zeros pooled[seg][*] ----
__global__ void softmax_kernel(const float* __restrict__ s,
                               const int* __restrict__ segstart,
                               float* __restrict__ att,
                               float* __restrict__ pooled) {
  int seg = blockIdx.x;
  int st = segstart[seg], en = segstart[seg + 1];
  int t = threadIdx.x;
  for (int c = t; c < DIM; c += 256) pooled[(size_t)seg * DIM + c] = 0.f;
  __shared__ float red[8];
  float m = -1e30f;
  for (int i = st + t; i < en; i += 256) m = fmaxf(m, s[i]);
  for (int d = 1; d < 64; d <<= 1) m = fmaxf(m, __shfl_xor(m, d));
  if ((t & 63) == 0) red[t >> 6] = m;
  __syncthreads();
  m = fmaxf(fmaxf(red[0], red[1]), fmaxf(red[2], red[3]));
  float z = 0.f;
  for (int i = st + t; i < en; i += 256) z += __expf(s[i] - m);
  for (int d = 1; d < 64; d <<= 1) z += __shfl_xor(z, d);
  if ((t & 63) == 0) red[4 + (t >> 6)] = z;
  __syncthreads();
  z = red[4] + red[5] + red[6] + red[7];
  float rz = 1.0f / z;
  for (int i = st + t; i < en; i += 256) att[i] = __expf(s[i] - m) * rz;
}

// ---- attention-weighted pooling from f16 features ----
__global__ void pool_kernel(const _Float16* __restrict__ F,
                            const float* __restrict__ att,
                            const int* __restrict__ segstart,
                            float* __restrict__ pooled) {
  int seg = blockIdx.x, part = blockIdx.y;
  int st = segstart[seg], en = segstart[seg + 1];
  int len = en - st;
  int chunk = (len + 7) >> 3;
  int r0 = st + chunk * part;
  int r1 = min(en, r0 + chunk);
  int t = threadIdx.x;
  float acc[4] = {0.f, 0.f, 0.f, 0.f};
  int r = r0;
  for (; r + 2 <= r1; r += 2) {
    float a0 = att[r], a1 = att[r + 1];
    f16x4 f0 = ((const f16x4*)(F + (size_t)r * DIM))[t];
    f16x4 f1 = ((const f16x4*)(F + (size_t)(r + 1) * DIM))[t];
#pragma unroll
    for (int c = 0; c < 4; ++c) {
      acc[c] = fmaf(a0, (float)f0[c], acc[c]);
      acc[c] = fmaf(a1, (float)f1[c], acc[c]);
    }
  }
  if (r < r1) {
    float a0 = att[r];
    f16x4 f0 = ((const f16x4*)(F + (size_t)r * DIM))[t];
#pragma unroll
    for (int c = 0; c < 4; ++c) acc[c] = fmaf(a0, (float)f0[c], acc[c]);
  }
  float* dst = pooled + (size_t)seg * DIM + t * 4;
#pragma unroll
  for (int c = 0; c < 4; ++c) atomicAdd(dst + c, acc[c]);
}

// ---- head layer 1: h = relu(pooled @ W1^T + b1), [128,512] ----
__global__ void head1_kernel(const float* __restrict__ pooled,
                             const float* __restrict__ W1,
                             const float* __restrict__ b1, float* __restrict__ h) {
  int og = blockIdx.x, sg = blockIdx.y;
  __shared__ float Wt[16 * 65];
  __shared__ float Pt[32 * 65];
  int t = threadIdx.x;
  int tx = t & 15, ty = t >> 4;
  float acc0 = 0.f, acc1 = 0.f;
  for (int kcc = 0; kcc < 20; ++kcc) {
    __syncthreads();
#pragma unroll
    for (int u = 0; u < 4; ++u) {
      int lin = t + 256 * u;
      int o = lin >> 6, kk = lin & 63;
      Wt[o * 65 + kk] = W1[(size_t)(og * 16 + o) * DIM + kcc * 64 + kk];
    }
#pragma unroll
    for (int u = 0; u < 8; ++u) {
      int lin = t + 256 * u;
      int ss = lin >> 6, kk = lin & 63;
      Pt[ss * 65 + kk] = pooled[(size_t)(sg * 32 + ss) * DIM + kcc * 64 + kk];
    }
    __syncthreads();
#pragma unroll
    for (int kk = 0; kk < 64; ++kk) {
      float wv = Wt[tx * 65 + kk];
      acc0 = fmaf(Pt[ty * 65 + kk], wv, acc0);
      acc1 = fmaf(Pt[(ty + 16) * 65 + kk], wv, acc1);
    }
  }
  int o = og * 16 + tx;
  float bias = b1[o];
  h[(size_t)(sg * 32 + ty) * DHEAD + o] = fmaxf(acc0 + bias, 0.f);
  h[(size_t)(sg * 32 + ty + 16) * DHEAD + o] = fmaxf(acc1 + bias, 0.f);
}

// ---- head layer 2: out[seg] = relu_h[seg] . W2 + b2 ----
__global__ void head2_kernel(const float* __restrict__ h,
                             const float* __restrict__ W2,
                             const float* __restrict__ b2, float* __restrict__ out) {
  int seg = blockIdx.x;
  int t = threadIdx.x;
  float val = h[(size_t)seg * DHEAD + t] * W2[t] +
              h[(size_t)seg * DHEAD + t + 256] * W2[t + 256];
  for (int d = 1; d < 64; d <<= 1) val += __shfl_xor(val, d);
  __shared__ float red[4];
  if ((t & 63) == 0) red[t >> 6] = val;
  __syncthreads();
  if (t == 0) out[seg] = red[0] + red[1] + red[2] + red[3] + b2[0];
}

extern "C" void kernel_launch(void* const* d_in, const int* in_sizes, int n_in,
                              void* d_out, int out_size, void* d_ws, size_t ws_size,
                              hipStream_t stream) {
  const float* features = (const float*)d_in[0];
  const float* Ww = (const float*)d_in[1];
  const float* bw = (const float*)d_in[2];
  const float* v = (const float*)d_in[3];
  const float* W1 = (const float*)d_in[4];
  const float* b1 = (const float*)d_in[5];
  const float* W2 = (const float*)d_in[6];
  const float* b2 = (const float*)d_in[7];
  const int* segids = (const int*)d_in[8];
  float* out = (float*)d_out;

  char* ws = (char*)d_ws;
  _Float16* Xh = (_Float16*)(ws + OFF_XH);
  _Float16* Wh = (_Float16*)(ws + OFF_WH);
  float* s = (float*)(ws + OFF_S);
  float* att = (float*)(ws + OFF_ATT);
  int* segstart = (int*)(ws + OFF_SEG);
  float* pooled = (float*)(ws + OFF_POOL);
  float* h = (float*)(ws + OFF_H);

  const int na8 = TOTAL_ROWS * DIM / 8;   // 5242880
  const int nb8 = DIM * DIM / 8;          // 204800
  cvt_f16_kernel<<<(na8 + nb8 + 255) / 256, 256, 0, stream>>>(features, Xh, na8,
                                                              Ww, Wh, nb8);
  segstart_kernel<<<TOTAL_ROWS / 256, 256, 0, stream>>>(segids, segstart, s,
                                                        TOTAL_ROWS);

  dim3 ggrid(TOTAL_ROWS / 128, DIM / 128);
  gemm_s_kernel<<<ggrid, 256, 0, stream>>>(Xh, Wh, v, bw, s);

  softmax_kernel<<<NSEG, 256, 0, stream>>>(s, segstart, att, pooled);
  pool_kernel<<<dim3(NSEG, 8), 320, 0, stream>>>(Xh, att, segstart, pooled);
  head1_kernel<<<dim3(32, 4), 256, 0, stream>>>(pooled, W1, b1, h);
  head2_kernel<<<NSEG, 256, 0, stream>>>(h, W2, b2, out);
}

// Round 6
// 474.347 us; speedup vs baseline: 1.0538x; 1.0538x over previous
//
#include <hip/hip_runtime.h>
#include <hip/hip_bf16.h>

// ---------------------------------------------------------------------------
// ATTEfficient: s = tanh(X@Ww^T + bw)@v ; segment softmax ; att-pool ; MLP head
// X: [32768,1280] f32, Ww: [1280,1280], v: [1280], W1: [512,1280], W2: [1,512]
// ---------------------------------------------------------------------------

#define TOTAL_ROWS 32768
#define DIM 1280
#define NSEG 128
#define DHEAD 512

typedef _Float16 f16x8 __attribute__((ext_vector_type(8)));
typedef _Float16 f16x4 __attribute__((ext_vector_type(4)));
typedef float f32x4 __attribute__((ext_vector_type(4)));

// ---- workspace layout (bytes) ----
#define OFF_XH   0                            // 32768*1280*2 = 83886080
#define OFF_WH   83886080                     // 1280*1280*2  = 3276800
#define OFF_S    87162880                     // 32768*4      = 131072
#define OFF_SEG  87425024                     // 132*4 -> pad 1024
#define OFF_POOL 87426048                     // 128*1280*4   = 655360
#define OFF_H    88081408                     // 128*512*4    = 262144

__device__ __forceinline__ void load_lds16(const void* g, void* l) {
  __builtin_amdgcn_global_load_lds(
      (const __attribute__((address_space(1))) unsigned int*)g,
      (__attribute__((address_space(3))) unsigned int*)l, 16, 0, 0);
}

__device__ __forceinline__ float tanh_fast(float x) {
  float e = __expf(2.0f * x);
  return 1.0f - 2.0f * __builtin_amdgcn_rcpf(e + 1.0f);
}

// ---- f32->f16 cvt for X and W + all buffer init + segstart, one launch ----
__global__ void cvt_init_kernel(const float* __restrict__ a, _Float16* __restrict__ oa,
                                int na8, const float* __restrict__ b,
                                _Float16* __restrict__ ob, int nb8,
                                const int* __restrict__ sid,
                                int* __restrict__ segstart, float* __restrict__ s,
                                float* __restrict__ pooled) {
  int i = blockIdx.x * blockDim.x + threadIdx.x;
  // init duties (ws is 0xAA-poisoned before every launch)
  if (i < TOTAL_ROWS) {
    s[i] = 0.f;
    int sg = sid[i];
    if (i == 0) segstart[0] = 0;
    else if (sid[i - 1] != sg) segstart[sg] = i;
    if (i == TOTAL_ROWS - 1) segstart[sg + 1] = TOTAL_ROWS;
  }
  if (i < NSEG * DIM) pooled[i] = 0.f;
  // conversion duties
  const float* in;
  _Float16* out;
  int idx;
  if (i < na8) {
    in = a; out = oa; idx = i;
  } else {
    idx = i - na8;
    if (idx >= nb8) return;
    in = b; out = ob;
  }
  const float4* p = (const float4*)in + (size_t)idx * 2;
  float4 u0 = p[0], u1 = p[1];
  f16x8 h;
  h[0] = (_Float16)u0.x; h[1] = (_Float16)u0.y;
  h[2] = (_Float16)u0.z; h[3] = (_Float16)u0.w;
  h[4] = (_Float16)u1.x; h[5] = (_Float16)u1.y;
  h[6] = (_Float16)u1.z; h[7] = (_Float16)u1.w;
  *((f16x8*)out + idx) = h;
}

// ---- fused GEMM + tanh + dot-with-v:  s[i] += sum_j tanh(X_i.W_j + bw_j) v_j
// tile 128x128, BK=64, XOR-swizzled LDS (0 conflicts), 16x16x32 MFMA,
// minimal live registers (R4 structure — best measured: 145.6 us).
__global__ __launch_bounds__(256) void gemm_s_kernel(
    const _Float16* __restrict__ X, const _Float16* __restrict__ W,
    const float* __restrict__ v, const float* __restrict__ bw,
    float* __restrict__ s) {
  __shared__ _Float16 As[128 * 64];   // 16 KB, [row][64], chunk-swizzled
  __shared__ _Float16 Bs[128 * 64];   // 16 KB
  const int rowBase = blockIdx.x * 128;
  const int jBase = blockIdx.y * 128;
  const int t = threadIdx.x;
  const int lane = t & 63;
  const int w = t >> 6;
  const int wm = w & 1, wn = w >> 1;
  const int kc = lane >> 4;     // 16B chunk within a 32-wide k-step
  const int lm = lane & 15;

  // LDS fragment base offsets (f16 units); row%8 == lm%8 makes the swizzle
  // index mt-invariant: full offset = base[s2] + mt*1024 (ds_read imm 2048*mt)
  int aBase[2], bBase[2];
#pragma unroll
  for (int s2 = 0; s2 < 2; ++s2) {
    int swz = ((kc + s2 * 4 + lm) & 7) * 8;
    aBase[s2] = (wm * 64 + lm) * 64 + swz;
    bBase[s2] = (wn * 64 + lm) * 64 + swz;
  }

  // staging: slot l = w*256 + q*64 + lane holds chunk g of row w*32+q*8+(lane>>3)
  const int subrow = lane >> 3;
  const int g = ((lane & 7) - subrow) & 7;
  const _Float16* gA = X + (size_t)(rowBase + w * 32 + subrow) * DIM + g * 8;
  const _Float16* gB = W + (size_t)(jBase + w * 32 + subrow) * DIM + g * 8;

  f32x4 acc[4][4];
  const f32x4 zero = {0.f, 0.f, 0.f, 0.f};
#pragma unroll
  for (int i = 0; i < 4; ++i)
#pragma unroll
    for (int j = 0; j < 4; ++j) acc[i][j] = zero;

  for (int k0 = 0; k0 < DIM; k0 += 64) {
    __syncthreads();
#pragma unroll
    for (int q = 0; q < 4; ++q) {
      load_lds16(gA + k0 + q * (8 * DIM), &As[(w * 256 + q * 64) * 8]);
      load_lds16(gB + k0 + q * (8 * DIM), &Bs[(w * 256 + q * 64) * 8]);
    }
    __syncthreads();

#pragma unroll
    for (int s2 = 0; s2 < 2; ++s2) {
      f16x8 a[4], b[4];
#pragma unroll
      for (int mt = 0; mt < 4; ++mt) {
        a[mt] = *(const f16x8*)&As[aBase[s2] + mt * 1024];
        b[mt] = *(const f16x8*)&Bs[bBase[s2] + mt * 1024];
      }
#pragma unroll
      for (int mt = 0; mt < 4; ++mt)
#pragma unroll
        for (int nt = 0; nt < 4; ++nt)
          acc[mt][nt] = __builtin_amdgcn_mfma_f32_16x16x32_f16(
              a[mt], b[nt], acc[mt][nt], 0, 0, 0);
    }
  }

  // epilogue: C/D layout col=lane&15, row=(lane>>4)*4+reg
  const int colBase = jBase + wn * 64 + lm;
  float vv[4], bb[4];
#pragma unroll
  for (int nt = 0; nt < 4; ++nt) {
    int j = colBase + nt * 16;
    vv[nt] = v[j];
    bb[nt] = bw[j];
  }
  const int gq = lane >> 4;
#pragma unroll
  for (int mt = 0; mt < 4; ++mt) {
#pragma unroll
    for (int r = 0; r < 4; ++r) {
      float sumv = 0.f;
#pragma unroll
      for (int nt = 0; nt < 4; ++nt)
        sumv += tanh_fast(acc[mt][nt][r] + bb[nt]) * vv[nt];
      sumv += __shfl_xor(sumv, 1);
      sumv += __shfl_xor(sumv, 2);
      sumv += __shfl_xor(sumv, 4);
      sumv += __shfl_xor(sumv, 8);
      if (lm == 0) {
        int row = rowBase + wm * 64 + mt * 16 + gq * 4 + r;
        atomicAdd(&s[row], sumv);
      }
    }
  }
}

// ---- fused softmax + attention pooling ----
// grid (128 segs, 8 row-parts), block 320. Each block recomputes the segment
// softmax stats (m, z) from s (<=448 L2-hot floats), then pools its row part
// with att computed on the fly. Deterministic across parts (same math).
__global__ void softpool_kernel(const _Float16* __restrict__ F,
                                const float* __restrict__ s,
                                const int* __restrict__ segstart,
                                float* __restrict__ pooled) {
  int seg = blockIdx.x, part = blockIdx.y;
  int st = segstart[seg], en = segstart[seg + 1];
  int t = threadIdx.x;
  __shared__ float redm[5], redz[5];
  float m = -1e30f;
  for (int i = st + t; i < en; i += 320) m = fmaxf(m, s[i]);
  for (int d = 1; d < 64; d <<= 1) m = fmaxf(m, __shfl_xor(m, d));
  if ((t & 63) == 0) redm[t >> 6] = m;
  __syncthreads();
  m = fmaxf(fmaxf(fmaxf(redm[0], redm[1]), fmaxf(redm[2], redm[3])), redm[4]);
  float z = 0.f;
  for (int i = st + t; i < en; i += 320) z += __expf(s[i] - m);
  for (int d = 1; d < 64; d <<= 1) z += __shfl_xor(z, d);
  if ((t & 63) == 0) redz[t >> 6] = z;
  __syncthreads();
  z = redz[0] + redz[1] + redz[2] + redz[3] + redz[4];
  float rz = 1.0f / z;

  int len = en - st;
  int chunk = (len + 7) >> 3;
  int r0 = st + chunk * part;
  int r1 = min(en, r0 + chunk);
  float acc[4] = {0.f, 0.f, 0.f, 0.f};
  int r = r0;
  for (; r + 2 <= r1; r += 2) {
    float a0 = __expf(s[r] - m) * rz;
    float a1 = __expf(s[r + 1] - m) * rz;
    f16x4 f0 = ((const f16x4*)(F + (size_t)r * DIM))[t];
    f16x4 f1 = ((const f16x4*)(F + (size_t)(r + 1) * DIM))[t];
#pragma unroll
    for (int c = 0; c < 4; ++c) {
      acc[c] = fmaf(a0, (float)f0[c], acc[c]);
      acc[c] = fmaf(a1, (float)f1[c], acc[c]);
    }
  }
  if (r < r1) {
    float a0 = __expf(s[r] - m) * rz;
    f16x4 f0 = ((const f16x4*)(F + (size_t)r * DIM))[t];
#pragma unroll
    for (int c = 0; c < 4; ++c) acc[c] = fmaf(a0, (float)f0[c], acc[c]);
  }
  float* dst = pooled + (size_t)seg * DIM + t * 4;
#pragma unroll
  for (int c = 0; c < 4; ++c) atomicAdd(dst + c, acc[c]);
}

// ---- head layer 1: h = relu(pooled @ W1^T + b1), [128,512] ----
__global__ void head1_kernel(const float* __restrict__ pooled,
                             const float* __restrict__ W1,
                             const float* __restrict__ b1, float* __restrict__ h) {
  int og = blockIdx.x, sg = blockIdx.y;
  __shared__ float Wt[16 * 65];
  __shared__ float Pt[32 * 65];
  int t = threadIdx.x;
  int tx = t & 15, ty = t >> 4;
  float acc0 = 0.f, acc1 = 0.f;
  for (int kcc = 0; kcc < 20; ++kcc) {
    __syncthreads();
#pragma unroll
    for (int u = 0; u < 4; ++u) {
      int lin = t + 256 * u;
      int o = lin >> 6, kk = lin & 63;
      Wt[o * 65 + kk] = W1[(size_t)(og * 16 + o) * DIM + kcc * 64 + kk];
    }
#pragma unroll
    for (int u = 0; u < 8; ++u) {
      int lin = t + 256 * u;
      int ss = lin >> 6, kk = lin & 63;
      Pt[ss * 65 + kk] = pooled[(size_t)(sg * 32 + ss) * DIM + kcc * 64 + kk];
    }
    __syncthreads();
#pragma unroll
    for (int kk = 0; kk < 64; ++kk) {
      float wv = Wt[tx * 65 + kk];
      acc0 = fmaf(Pt[ty * 65 + kk], wv, acc0);
      acc1 = fmaf(Pt[(ty + 16) * 65 + kk], wv, acc1);
    }
  }
  int o = og * 16 + tx;
  float bias = b1[o];
  h[(size_t)(sg * 32 + ty) * DHEAD + o] = fmaxf(acc0 + bias, 0.f);
  h[(size_t)(sg * 32 + ty + 16) * DHEAD + o] = fmaxf(acc1 + bias, 0.f);
}

// ---- head layer 2: out[seg] = relu_h[seg] . W2 + b2 ----
__global__ void head2_kernel(const float* __restrict__ h,
                             const float* __restrict__ W2,
                             const float* __restrict__ b2, float* __restrict__ out) {
  int seg = blockIdx.x;
  int t = threadIdx.x;
  float val = h[(size_t)seg * DHEAD + t] * W2[t] +
              h[(size_t)seg * DHEAD + t + 256] * W2[t + 256];
  for (int d = 1; d < 64; d <<= 1) val += __shfl_xor(val, d);
  __shared__ float red[4];
  if ((t & 63) == 0) red[t >> 6] = val;
  __syncthreads();
  if (t == 0) out[seg] = red[0] + red[1] + red[2] + red[3] + b2[0];
}

extern "C" void kernel_launch(void* const* d_in, const int* in_sizes, int n_in,
                              void* d_out, int out_size, void* d_ws, size_t ws_size,
                              hipStream_t stream) {
  const float* features = (const float*)d_in[0];
  const float* Ww = (const float*)d_in[1];
  const float* bw = (const float*)d_in[2];
  const float* v = (const float*)d_in[3];
  const float* W1 = (const float*)d_in[4];
  const float* b1 = (const float*)d_in[5];
  const float* W2 = (const float*)d_in[6];
  const float* b2 = (const float*)d_in[7];
  const int* segids = (const int*)d_in[8];
  float* out = (float*)d_out;

  char* ws = (char*)d_ws;
  _Float16* Xh = (_Float16*)(ws + OFF_XH);
  _Float16* Wh = (_Float16*)(ws + OFF_WH);
  float* s = (float*)(ws + OFF_S);
  int* segstart = (int*)(ws + OFF_SEG);
  float* pooled = (float*)(ws + OFF_POOL);
  float* h = (float*)(ws + OFF_H);

  const int na8 = TOTAL_ROWS * DIM / 8;   // 5242880
  const int nb8 = DIM * DIM / 8;          // 204800
  cvt_init_kernel<<<(na8 + nb8 + 255) / 256, 256, 0, stream>>>(
      features, Xh, na8, Ww, Wh, nb8, segids, segstart, s, pooled);

  dim3 ggrid(TOTAL_ROWS / 128, DIM / 128);
  gemm_s_kernel<<<ggrid, 256, 0, stream>>>(Xh, Wh, v, bw, s);

  softpool_kernel<<<dim3(NSEG, 8), 320, 0, stream>>>(Xh, s, segstart, pooled);
  head1_kernel<<<dim3(32, 4), 256, 0, stream>>>(pooled, W1, b1, h);
  head2_kernel<<<NSEG, 256, 0, stream>>>(h, W2, b2, out);
}